// Round 1
// baseline (614.823 us; speedup 1.0000x reference)
//
#include <hip/hip_runtime.h>

// MHA: B=4, S=2048, D=1024, H=16, dk=64.
// Pipeline: cast f32->bf16, pack mask bits, 3 proj GEMMs (head-major out),
// V transpose, flash attention, output GEMM (f32 out).

typedef __attribute__((ext_vector_type(8))) short frag8;   // 8 bf16 = 4 VGPR
typedef __attribute__((ext_vector_type(4))) float f32x4;

#define MFMA16(a,b,c) __builtin_amdgcn_mfma_f32_16x16x32_bf16((a),(b),(c),0,0,0)

__device__ __forceinline__ short f2bf(float f) {
  union { float f; unsigned u; } x; x.f = f;
  unsigned r = (x.u + 0x7fffu + ((x.u >> 16) & 1u)) >> 16;  // RNE
  return (short)r;
}

__device__ __forceinline__ void gl16(const void* g, void* l) {
  __builtin_amdgcn_global_load_lds(
      (const __attribute__((address_space(1))) unsigned*)g,
      (__attribute__((address_space(3))) unsigned*)l, 16, 0, 0);
}

// ---------------- cast f32 -> bf16 (vectorized x4) ----------------
__global__ __launch_bounds__(256) void cast_f32_bf16(
    const float* __restrict__ src, short* __restrict__ dst, int n4) {
  int i = blockIdx.x * 256 + threadIdx.x;
  if (i >= n4) return;
  float4 f = ((const float4*)src)[i];
  short4 o;
  o.x = f2bf(f.x); o.y = f2bf(f.y); o.z = f2bf(f.z); o.w = f2bf(f.w);
  ((short4*)dst)[i] = o;
}

// ---------------- mask int32 -> bitpack via ballot ----------------
// bits[row*32 + c/64] : bit j of 64-chunk = mask[row][c+j] != 0
__global__ __launch_bounds__(256) void pack_mask(
    const int* __restrict__ mask, unsigned long long* __restrict__ bits) {
  int wv = threadIdx.x >> 6, l = threadIdx.x & 63;
  size_t row = (size_t)blockIdx.x * 4 + wv;   // 0..8191 = b*2048+q
  const int* src = mask + row * 2048;
  for (int c = 0; c < 2048; c += 64) {
    unsigned long long bl = __ballot(src[c + l] != 0);
    if (l == 0) bits[row * 32 + (c >> 6)] = bl;
  }
}

// ---------------- GEMM: out[m][n] = sum_k A[m][k]*W[n][k] ----------------
// A: [M=8192][1024] bf16, W: [1024][1024] bf16.
// MODE 0: bf16 out, head-major [B][H][S][64]. MODE 1: f32 out [M][1024].
template <int MODE>
__global__ __launch_bounds__(256) void gemm_bt(
    const short* __restrict__ A, const short* __restrict__ W,
    void* __restrict__ outp) {
  __shared__ short As[2][128 * 32];
  __shared__ short Bs[2][128 * 32];
  const int t = threadIdx.x;
  const int l = t & 63, wv = t >> 6;
  const int lg = l >> 4, lr = l & 15;
  const int wm = (wv >> 1) * 64, wn = (wv & 1) * 64;
  const int m0 = (blockIdx.x >> 3) * 128;
  const int n0 = (blockIdx.x & 7) * 128;

  auto stage = [&](int buf, int kt) {
    const int k0 = kt * 32;
#pragma unroll
    for (int c = 0; c < 2; ++c) {
      int idx = c * 256 + t;              // 16B units over 8KB tile
      int row = idx >> 2, ch = (idx & 3) * 8;
      gl16(A + (size_t)(m0 + row) * 1024 + k0 + ch, &As[buf][idx * 8]);
      gl16(W + (size_t)(n0 + row) * 1024 + k0 + ch, &Bs[buf][idx * 8]);
    }
  };

  f32x4 acc[4][4] = {};
  stage(0, 0);
  asm volatile("s_waitcnt vmcnt(0)" ::: "memory");
  __syncthreads();
  int buf = 0;
  for (int kt = 0; kt < 32; ++kt) {
    if (kt + 1 < 32) stage(buf ^ 1, kt + 1);
    frag8 af[4], bf[4];
#pragma unroll
    for (int i = 0; i < 4; ++i) {
      af[i] = *(const frag8*)&As[buf][(wm + i * 16 + lr) * 32 + 8 * lg];
      bf[i] = *(const frag8*)&Bs[buf][(wn + i * 16 + lr) * 32 + 8 * lg];
    }
#pragma unroll
    for (int mi = 0; mi < 4; ++mi)
#pragma unroll
      for (int ni = 0; ni < 4; ++ni)
        acc[mi][ni] = MFMA16(af[mi], bf[ni], acc[mi][ni]);
    asm volatile("s_waitcnt vmcnt(0)" ::: "memory");
    __syncthreads();
    buf ^= 1;
  }

#pragma unroll
  for (int mi = 0; mi < 4; ++mi)
#pragma unroll
    for (int ni = 0; ni < 4; ++ni)
#pragma unroll
      for (int r = 0; r < 4; ++r) {
        int m = m0 + wm + mi * 16 + 4 * lg + r;
        int n = n0 + wn + ni * 16 + lr;
        if (MODE == 0) {
          int b = m >> 11, s = m & 2047, h = n >> 6, dk = n & 63;
          ((short*)outp)[(((size_t)b * 16 + h) * 2048 + s) * 64 + dk] =
              f2bf(acc[mi][ni][r]);
        } else {
          ((float*)outp)[(size_t)m * 1024 + n] = acc[mi][ni][r];
        }
      }
}

// ---------------- V [bh][s][64] -> Vt [bh][64][s] ----------------
__global__ __launch_bounds__(256) void transpose_v(
    const short* __restrict__ Vp, short* __restrict__ Vt) {
  __shared__ short lds[64 * 72];
  int bh = blockIdx.y, s0 = blockIdx.x * 64;
  int t = threadIdx.x;
  int rr = t >> 3, c0 = (t & 7) * 8;
#pragma unroll
  for (int half = 0; half < 2; ++half) {
    int r = half * 32 + rr;
    frag8 v = *(const frag8*)(Vp + ((size_t)bh * 2048 + s0 + r) * 64 + c0);
#pragma unroll
    for (int j = 0; j < 8; ++j) lds[r * 72 + c0 + j] = v[j];
  }
  __syncthreads();
#pragma unroll
  for (int half = 0; half < 2; ++half) {
    int d = half * 32 + rr;
    frag8 o;
#pragma unroll
    for (int j = 0; j < 8; ++j) o[j] = lds[(c0 + j) * 72 + d];
    *(frag8*)(Vt + ((size_t)bh * 64 + d) * 2048 + s0 + c0) = o;
  }
}

// ---------------- flash attention ----------------
// block = (b,h, 128 q rows); 4 waves x 32 rows; BKV=32.
__global__ __launch_bounds__(256) void attn_fwd(
    const short* __restrict__ Qp, const short* __restrict__ Kp,
    const short* __restrict__ Vt, const unsigned* __restrict__ mbits,
    short* __restrict__ X) {
  __shared__ short Ks[2][32 * 64];   // [kv][d]
  __shared__ short Vs[2][64 * 32];   // [d][kv]
  __shared__ short Ps[4][32 * 32];   // per-wave P [q][kv]

  const int bid = blockIdx.x;
  const int qt = bid & 15;
  const int bh = bid >> 4;
  const int b = bh >> 4, h = bh & 15;
  const int t = threadIdx.x;
  const int l = t & 63, wv = t >> 6;
  const int lg = l >> 4, lr = l & 15;
  const int q0 = qt * 128 + wv * 32;

  frag8 qf[2][2];
  const short* Qb = Qp + ((size_t)bh * 2048 + q0) * 64;
#pragma unroll
  for (int mb = 0; mb < 2; ++mb)
#pragma unroll
    for (int kc = 0; kc < 2; ++kc)
      qf[mb][kc] = *(const frag8*)(Qb + (mb * 16 + lr) * 64 + kc * 32 + 8 * lg);

  f32x4 acc[2][4] = {};
  float mrun[2][4], lrun[2][4];
#pragma unroll
  for (int mb = 0; mb < 2; ++mb)
#pragma unroll
    for (int r = 0; r < 4; ++r) { mrun[mb][r] = -1e30f; lrun[mb][r] = 0.f; }

  const size_t kbase = (size_t)bh * 2048 * 64;
  const size_t vbase = (size_t)bh * 64 * 2048;
  auto stage = [&](int buf, int kt) {
    int row = t >> 3, ch = (t & 7) * 8;          // K tile 32x64
    gl16(Kp + kbase + (size_t)(kt * 32 + row) * 64 + ch, &Ks[buf][t * 8]);
    int vrow = t >> 2, vch = (t & 3) * 8;        // Vt tile 64x32
    gl16(Vt + vbase + (size_t)vrow * 2048 + kt * 32 + vch, &Vs[buf][t * 8]);
  };

  stage(0, 0);
  asm volatile("s_waitcnt vmcnt(0)" ::: "memory");
  __syncthreads();
  int buf = 0;
  const int qrow_base = b << 11;

  for (int kt = 0; kt < 64; ++kt) {
    if (kt + 1 < 64) stage(buf ^ 1, kt + 1);
    // QK^T
    frag8 kf[2][2];
#pragma unroll
    for (int nb = 0; nb < 2; ++nb)
#pragma unroll
      for (int kc = 0; kc < 2; ++kc)
        kf[nb][kc] =
            *(const frag8*)&Ks[buf][(nb * 16 + lr) * 64 + kc * 32 + 8 * lg];
    f32x4 s[2][2] = {};
#pragma unroll
    for (int mb = 0; mb < 2; ++mb)
#pragma unroll
      for (int nb = 0; nb < 2; ++nb) {
        s[mb][nb] = MFMA16(qf[mb][0], kf[nb][0], s[mb][nb]);
        s[mb][nb] = MFMA16(qf[mb][1], kf[nb][1], s[mb][nb]);
      }
    // masked online softmax (rows = 4*lg+r, cols = lr+16*nb)
#pragma unroll
    for (int mb = 0; mb < 2; ++mb) {
      unsigned mw[4];
#pragma unroll
      for (int r = 0; r < 4; ++r) {
        int qabs = qt * 128 + wv * 32 + mb * 16 + 4 * lg + r;
        mw[r] = mbits[((size_t)(qrow_base + qabs) << 6) + kt];
      }
      float pv[2][4], fac[4];
#pragma unroll
      for (int r = 0; r < 4; ++r) {
        float v0 = s[mb][0][r] * 0.125f;
        float v1 = s[mb][1][r] * 0.125f;
        v0 = ((mw[r] >> lr) & 1u) ? v0 : -1e30f;
        v1 = ((mw[r] >> (lr + 16)) & 1u) ? v1 : -1e30f;
        float tm = fmaxf(v0, v1);
#pragma unroll
        for (int msk = 1; msk <= 8; msk <<= 1)
          tm = fmaxf(tm, __shfl_xor(tm, msk));
        float mn = fmaxf(mrun[mb][r], tm);
        float f = __expf(mrun[mb][r] - mn);
        mrun[mb][r] = mn;
        fac[r] = f;
        float p0 = __expf(v0 - mn);
        float p1 = __expf(v1 - mn);
        pv[0][r] = p0; pv[1][r] = p1;
        float rs = p0 + p1;
#pragma unroll
        for (int msk = 1; msk <= 8; msk <<= 1) rs += __shfl_xor(rs, msk);
        lrun[mb][r] = lrun[mb][r] * f + rs;
      }
#pragma unroll
      for (int r = 0; r < 4; ++r) {
        Ps[wv][(mb * 16 + 4 * lg + r) * 32 + lr] = f2bf(pv[0][r]);
        Ps[wv][(mb * 16 + 4 * lg + r) * 32 + 16 + lr] = f2bf(pv[1][r]);
      }
#pragma unroll
      for (int db = 0; db < 4; ++db)
#pragma unroll
        for (int r = 0; r < 4; ++r) acc[mb][db][r] *= fac[r];
    }
    // PV (P via per-wave LDS, in-order DS within wave -> no barrier)
    frag8 vf[4];
#pragma unroll
    for (int db = 0; db < 4; ++db)
      vf[db] = *(const frag8*)&Vs[buf][(db * 16 + lr) * 32 + 8 * lg];
#pragma unroll
    for (int mb = 0; mb < 2; ++mb) {
      frag8 pf = *(const frag8*)&Ps[wv][(mb * 16 + lr) * 32 + 8 * lg];
#pragma unroll
      for (int db = 0; db < 4; ++db)
        acc[mb][db] = MFMA16(pf, vf[db], acc[mb][db]);
    }
    asm volatile("s_waitcnt vmcnt(0)" ::: "memory");
    __syncthreads();
    buf ^= 1;
  }
  // epilogue: X[b][q][h*64+d] = acc / l
#pragma unroll
  for (int mb = 0; mb < 2; ++mb)
#pragma unroll
    for (int r = 0; r < 4; ++r) {
      float inv = 1.0f / fmaxf(lrun[mb][r], 1e-30f);
      int qabs = qt * 128 + wv * 32 + mb * 16 + 4 * lg + r;
      size_t base = (size_t)(qrow_base + qabs) * 1024 + h * 64;
#pragma unroll
      for (int db = 0; db < 4; ++db)
        X[base + db * 16 + lr] = f2bf(acc[mb][db][r] * inv);
    }
}

// ---------------- launch ----------------
extern "C" void kernel_launch(void* const* d_in, const int* in_sizes, int n_in,
                              void* d_out, int out_size, void* d_ws,
                              size_t ws_size, hipStream_t stream) {
  const float* q  = (const float*)d_in[0];
  const float* k  = (const float*)d_in[1];
  const float* v  = (const float*)d_in[2];
  const int*  msk = (const int*)d_in[3];
  const float* Wq = (const float*)d_in[4];
  const float* Wk = (const float*)d_in[5];
  const float* Wv = (const float*)d_in[6];
  const float* Wo = (const float*)d_in[7];

  // workspace layout (bytes)
  const size_t SZ_T = 16777216;  // 8192*1024*2
  const size_t SZ_W = 2097152;   // 1024*1024*2
  char* ws = (char*)d_ws;
  short* qb  = (short*)(ws + 0 * SZ_T);
  short* kb  = (short*)(ws + 1 * SZ_T);
  short* vb  = (short*)(ws + 2 * SZ_T);
  short* Qp  = (short*)(ws + 3 * SZ_T);
  short* Kp  = (short*)(ws + 4 * SZ_T);
  short* Vp  = (short*)(ws + 5 * SZ_T);
  short* Vt  = (short*)(ws + 6 * SZ_T);
  short* X   = (short*)(ws + 7 * SZ_T);
  short* wqb = (short*)(ws + 8 * SZ_T);
  short* wkb = (short*)(ws + 8 * SZ_T + 1 * SZ_W);
  short* wvb = (short*)(ws + 8 * SZ_T + 2 * SZ_W);
  short* wob = (short*)(ws + 8 * SZ_T + 3 * SZ_W);
  void*  mb  = (void*)(ws + 8 * SZ_T + 4 * SZ_W);
  if (ws_size < 8 * SZ_T + 5 * SZ_W) return;  // visible failure if ws too small

  cast_f32_bf16<<<8192, 256, 0, stream>>>(q, qb, 2097152);
  cast_f32_bf16<<<8192, 256, 0, stream>>>(k, kb, 2097152);
  cast_f32_bf16<<<8192, 256, 0, stream>>>(v, vb, 2097152);
  cast_f32_bf16<<<1024, 256, 0, stream>>>(Wq, wqb, 262144);
  cast_f32_bf16<<<1024, 256, 0, stream>>>(Wk, wkb, 262144);
  cast_f32_bf16<<<1024, 256, 0, stream>>>(Wv, wvb, 262144);
  cast_f32_bf16<<<1024, 256, 0, stream>>>(Wo, wob, 262144);
  pack_mask<<<2048, 256, 0, stream>>>(msk, (unsigned long long*)mb);

  gemm_bt<0><<<512, 256, 0, stream>>>(qb, wqb, Qp);
  gemm_bt<0><<<512, 256, 0, stream>>>(kb, wkb, Kp);
  gemm_bt<0><<<512, 256, 0, stream>>>(vb, wvb, Vp);
  transpose_v<<<dim3(32, 64), 256, 0, stream>>>(Vp, Vt);
  attn_fwd<<<1024, 256, 0, stream>>>(Qp, Kp, Vt, (const unsigned*)mb, X);
  gemm_bt<1><<<512, 256, 0, stream>>>(X, wob, d_out);
}

// Round 2
// 359.124 us; speedup vs baseline: 1.7120x; 1.7120x over previous
//
#include <hip/hip_runtime.h>

// MHA: B=4, S=2048, D=1024, H=16, dk=64.
// cast f32->bf16, pack mask bits, 3 proj GEMMs (head-major out),
// V transpose, flash attention (swapped-QK^T, BKV=64, XOR-swizzled LDS),
// output GEMM (f32 out).

typedef __attribute__((ext_vector_type(8))) short frag8;   // 8 bf16 = 4 VGPR
typedef __attribute__((ext_vector_type(4))) float f32x4;
typedef unsigned long long ull;

#define MFMA16(a,b,c) __builtin_amdgcn_mfma_f32_16x16x32_bf16((a),(b),(c),0,0,0)

__device__ __forceinline__ short f2bf(float f) {
  union { float f; unsigned u; } x; x.f = f;
  unsigned r = (x.u + 0x7fffu + ((x.u >> 16) & 1u)) >> 16;  // RNE
  return (short)r;
}

__device__ __forceinline__ void gl16(const void* g, void* l) {
  __builtin_amdgcn_global_load_lds(
      (const __attribute__((address_space(1))) unsigned*)g,
      (__attribute__((address_space(3))) unsigned*)l, 16, 0, 0);
}

// ---------------- cast f32 -> bf16 (vectorized x4) ----------------
__global__ __launch_bounds__(256) void cast_f32_bf16(
    const float* __restrict__ src, short* __restrict__ dst, int n4) {
  int i = blockIdx.x * 256 + threadIdx.x;
  if (i >= n4) return;
  float4 f = ((const float4*)src)[i];
  short4 o;
  o.x = f2bf(f.x); o.y = f2bf(f.y); o.z = f2bf(f.z); o.w = f2bf(f.w);
  ((short4*)dst)[i] = o;
}

// ---------------- mask int32 -> bitpack via ballot ----------------
__global__ __launch_bounds__(256) void pack_mask(
    const int* __restrict__ mask, ull* __restrict__ bits) {
  int wv = threadIdx.x >> 6, l = threadIdx.x & 63;
  size_t row = (size_t)blockIdx.x * 4 + wv;   // 0..8191 = b*2048+q
  const int* src = mask + row * 2048;
  for (int c = 0; c < 2048; c += 64) {
    ull bl = __ballot(src[c + l] != 0);
    if (l == 0) bits[row * 32 + (c >> 6)] = bl;
  }
}

// ---------------- GEMM: out[m][n] = sum_k A[m][k]*W[n][k] ----------------
template <int MODE>
__global__ __launch_bounds__(256) void gemm_bt(
    const short* __restrict__ A, const short* __restrict__ W,
    void* __restrict__ outp) {
  __shared__ short As[2][128 * 32];
  __shared__ short Bs[2][128 * 32];
  const int t = threadIdx.x;
  const int l = t & 63, wv = t >> 6;
  const int lg = l >> 4, lr = l & 15;
  const int wm = (wv >> 1) * 64, wn = (wv & 1) * 64;
  const int m0 = (blockIdx.x >> 3) * 128;
  const int n0 = (blockIdx.x & 7) * 128;

  auto stage = [&](int buf, int kt) {
    const int k0 = kt * 32;
#pragma unroll
    for (int c = 0; c < 2; ++c) {
      int idx = c * 256 + t;
      int row = idx >> 2, ch = (idx & 3) * 8;
      gl16(A + (size_t)(m0 + row) * 1024 + k0 + ch, &As[buf][idx * 8]);
      gl16(W + (size_t)(n0 + row) * 1024 + k0 + ch, &Bs[buf][idx * 8]);
    }
  };

  f32x4 acc[4][4] = {};
  stage(0, 0);
  asm volatile("s_waitcnt vmcnt(0)" ::: "memory");
  __syncthreads();
  int buf = 0;
  for (int kt = 0; kt < 32; ++kt) {
    if (kt + 1 < 32) stage(buf ^ 1, kt + 1);
    frag8 af[4], bf[4];
#pragma unroll
    for (int i = 0; i < 4; ++i) {
      af[i] = *(const frag8*)&As[buf][(wm + i * 16 + lr) * 32 + 8 * lg];
      bf[i] = *(const frag8*)&Bs[buf][(wn + i * 16 + lr) * 32 + 8 * lg];
    }
#pragma unroll
    for (int mi = 0; mi < 4; ++mi)
#pragma unroll
      for (int ni = 0; ni < 4; ++ni)
        acc[mi][ni] = MFMA16(af[mi], bf[ni], acc[mi][ni]);
    asm volatile("s_waitcnt vmcnt(0)" ::: "memory");
    __syncthreads();
    buf ^= 1;
  }

#pragma unroll
  for (int mi = 0; mi < 4; ++mi)
#pragma unroll
    for (int ni = 0; ni < 4; ++ni)
#pragma unroll
      for (int r = 0; r < 4; ++r) {
        int m = m0 + wm + mi * 16 + 4 * lg + r;
        int n = n0 + wn + ni * 16 + lr;
        if (MODE == 0) {
          int b = m >> 11, s = m & 2047, h = n >> 6, dk = n & 63;
          ((short*)outp)[(((size_t)b * 16 + h) * 2048 + s) * 64 + dk] =
              f2bf(acc[mi][ni][r]);
        } else {
          ((float*)outp)[(size_t)m * 1024 + n] = acc[mi][ni][r];
        }
      }
}

// ---------------- V [bh][s][64] -> Vt [bh][64][s] ----------------
__global__ __launch_bounds__(256) void transpose_v(
    const short* __restrict__ Vp, short* __restrict__ Vt) {
  __shared__ short lds[64 * 72];
  int bh = blockIdx.y, s0 = blockIdx.x * 64;
  int t = threadIdx.x;
  int rr = t >> 3, c0 = (t & 7) * 8;
#pragma unroll
  for (int half = 0; half < 2; ++half) {
    int r = half * 32 + rr;
    frag8 v = *(const frag8*)(Vp + ((size_t)bh * 2048 + s0 + r) * 64 + c0);
#pragma unroll
    for (int j = 0; j < 8; ++j) lds[r * 72 + c0 + j] = v[j];
  }
  __syncthreads();
#pragma unroll
  for (int half = 0; half < 2; ++half) {
    int d = half * 32 + rr;
    frag8 o;
#pragma unroll
    for (int j = 0; j < 8; ++j) o[j] = lds[(c0 + j) * 72 + d];
    *(frag8*)(Vt + ((size_t)bh * 64 + d) * 2048 + s0 + c0) = o;
  }
}

// ---------------- flash attention (swapped QK^T) ----------------
// block = (b,h, 128 q rows); 4 waves x 32 q rows; BKV=64.
// S^T = mfma(K, Q): lane(lg,lr) holds S^T[kv=nb*16+4lg+r][q=qb*16+lr]
//   -> each lane owns 16 kv of ONE q-row; row-reduce = in-reg + 2 shfl.
// O^T = mfma(V^T, P): acc[db][qb] holds O^T[d=db*16+4lg+r][q=qb*16+lr].
// All LDS tiles 128B rows, XOR-swizzled: chunk16 ^= (row&7); gl16 stages
// with inverse-swizzled GLOBAL source (linear LDS dest, rule #21).
__global__ __launch_bounds__(256, 3) void attn_fwd(
    const short* __restrict__ Qp, const short* __restrict__ Kp,
    const short* __restrict__ Vt, const ull* __restrict__ mb64,
    short* __restrict__ X) {
  __shared__ short Ks[2][64 * 64];   // [kv][d]
  __shared__ short Vs[2][64 * 64];   // [d][kv]
  __shared__ short Ps[4][32 * 64];   // per-wave P [q][kv]

  const int bid = blockIdx.x;
  const int qt = bid & 15, bh = bid >> 4;
  const int b = bh >> 4, h = bh & 15;
  const int t = threadIdx.x;
  const int l = t & 63, wv = t >> 6;
  const int lg = l >> 4, lr = l & 15;
  const int q0 = qt * 128 + wv * 32;
  const int qrow_base = b << 11;

  // Q fragments (B-operand): Q[q=qb*16+lr][d=kc*32+8lg..+7]
  frag8 qf[2][2];
  const short* Qb = Qp + ((size_t)bh * 2048 + q0) * 64;
#pragma unroll
  for (int qb = 0; qb < 2; ++qb)
#pragma unroll
    for (int kc = 0; kc < 2; ++kc)
      qf[qb][kc] = *(const frag8*)(Qb + (qb * 16 + lr) * 64 + kc * 32 + 8 * lg);

  f32x4 acc[4][2] = {};
  float mrun[2] = {-1e30f, -1e30f}, lrun[2] = {0.f, 0.f};

  const size_t kbase = (size_t)bh * 2048 * 64;
  const size_t vbase = (size_t)bh * 64 * 2048;
  short* Pw = &Ps[wv][0];
  const int sx = lr & 7;  // row&7 for all blk*16+lr rows

  auto stage = [&](int buf, int kt) {
#pragma unroll
    for (int p = 0; p < 2; ++p) {
      int idx = p * 256 + t;          // 16B chunk over 8KB tile
      int row = idx >> 3, c = idx & 7;
      int cs = (c ^ (row & 7)) * 8;   // inverse-swizzled global source
      gl16(Kp + kbase + (size_t)(kt * 64 + row) * 64 + cs, &Ks[buf][idx * 8]);
      gl16(Vt + vbase + (size_t)row * 2048 + kt * 64 + cs, &Vs[buf][idx * 8]);
    }
  };

  stage(0, 0);
  asm volatile("s_waitcnt vmcnt(0)" ::: "memory");
  __syncthreads();
  int buf = 0;

  for (int kt = 0; kt < 32; ++kt) {
    if (kt + 1 < 32) stage(buf ^ 1, kt + 1);
    ull mw[2];
    mw[0] = mb64[(size_t)(qrow_base + q0 + lr) * 32 + kt];
    mw[1] = mb64[(size_t)(qrow_base + q0 + 16 + lr) * 32 + kt];

    // QK^T (swapped)
    f32x4 s[4][2] = {};
    __builtin_amdgcn_s_setprio(1);
#pragma unroll
    for (int nb = 0; nb < 4; ++nb) {
      const int ro = (nb * 16 + lr) * 64;
      frag8 k0 = *(const frag8*)&Ks[buf][ro + ((0 + lg) ^ sx) * 8];
      frag8 k1 = *(const frag8*)&Ks[buf][ro + ((4 + lg) ^ sx) * 8];
#pragma unroll
      for (int qb = 0; qb < 2; ++qb) {
        s[nb][qb] = MFMA16(k0, qf[qb][0], s[nb][qb]);
        s[nb][qb] = MFMA16(k1, qf[qb][1], s[nb][qb]);
      }
    }
    __builtin_amdgcn_s_setprio(0);

    // masked online softmax; lane's 16 kv values belong to q=qb*16+lr
#pragma unroll
    for (int qb = 0; qb < 2; ++qb) {
      float pv[4][4];
      float tm = -1e30f;
#pragma unroll
      for (int nb = 0; nb < 4; ++nb) {
        unsigned nib = (unsigned)(mw[qb] >> (nb * 16 + 4 * lg)) & 0xFu;
#pragma unroll
        for (int r = 0; r < 4; ++r) {
          float x = s[nb][qb][r] * 0.125f;
          x = ((nib >> r) & 1u) ? x : -1e30f;
          pv[nb][r] = x;
          tm = fmaxf(tm, x);
        }
      }
      tm = fmaxf(tm, __shfl_xor(tm, 16));
      tm = fmaxf(tm, __shfl_xor(tm, 32));
      float mn = fmaxf(mrun[qb], tm);
      float fac = __expf(mrun[qb] - mn);
      mrun[qb] = mn;
      float ts = 0.f;
#pragma unroll
      for (int nb = 0; nb < 4; ++nb)
#pragma unroll
        for (int r = 0; r < 4; ++r) {
          float e = __expf(pv[nb][r] - mn);
          pv[nb][r] = e;
          ts += e;
        }
      ts += __shfl_xor(ts, 16);
      ts += __shfl_xor(ts, 32);
      lrun[qb] = lrun[qb] * fac + ts;
#pragma unroll
      for (int db = 0; db < 4; ++db) {
        acc[db][qb][0] *= fac; acc[db][qb][1] *= fac;
        acc[db][qb][2] *= fac; acc[db][qb][3] *= fac;
      }
      // P[q][kv=16nb+4lg+r] as packed b64, swizzled
      const int q64 = (qb * 16 + lr) * 64;
#pragma unroll
      for (int nb = 0; nb < 4; ++nb) {
        short4 sv;
        sv.x = f2bf(pv[nb][0]); sv.y = f2bf(pv[nb][1]);
        sv.z = f2bf(pv[nb][2]); sv.w = f2bf(pv[nb][3]);
        int sw = ((2 * nb + (lg >> 1)) ^ sx) * 8 + 4 * (lg & 1);
        *(short4*)&Pw[q64 + sw] = sv;
      }
    }

    // PV: B-frag P[q=qb*16+lr][kv=kc*32+8lg..+7]
    frag8 pf[2][2];
#pragma unroll
    for (int qb = 0; qb < 2; ++qb)
#pragma unroll
      for (int kc = 0; kc < 2; ++kc)
        pf[qb][kc] = *(const frag8*)&Pw[(qb * 16 + lr) * 64 +
                                        ((kc * 4 + lg) ^ sx) * 8];
    __builtin_amdgcn_s_setprio(1);
#pragma unroll
    for (int db = 0; db < 4; ++db) {
      const int ro = (db * 16 + lr) * 64;
      frag8 v0 = *(const frag8*)&Vs[buf][ro + ((0 + lg) ^ sx) * 8];
      frag8 v1 = *(const frag8*)&Vs[buf][ro + ((4 + lg) ^ sx) * 8];
#pragma unroll
      for (int qb = 0; qb < 2; ++qb) {
        acc[db][qb] = MFMA16(v0, pf[qb][0], acc[db][qb]);
        acc[db][qb] = MFMA16(v1, pf[qb][1], acc[db][qb]);
      }
    }
    __builtin_amdgcn_s_setprio(0);

    asm volatile("s_waitcnt vmcnt(0)" ::: "memory");
    __syncthreads();
    buf ^= 1;
  }

  // epilogue: X[b][q][h*64+d] = O^T[d][q] / l ; d = db*16+4lg+r contiguous
#pragma unroll
  for (int qb = 0; qb < 2; ++qb) {
    float inv = 1.0f / fmaxf(lrun[qb], 1e-30f);
    int q = q0 + qb * 16 + lr;
    size_t base = (size_t)(qrow_base + q) * 1024 + h * 64 + 4 * lg;
#pragma unroll
    for (int db = 0; db < 4; ++db) {
      short4 o;
      o.x = f2bf(acc[db][qb][0] * inv);
      o.y = f2bf(acc[db][qb][1] * inv);
      o.z = f2bf(acc[db][qb][2] * inv);
      o.w = f2bf(acc[db][qb][3] * inv);
      *(short4*)&X[base + db * 16] = o;
    }
  }
}

// ---------------- launch ----------------
extern "C" void kernel_launch(void* const* d_in, const int* in_sizes, int n_in,
                              void* d_out, int out_size, void* d_ws,
                              size_t ws_size, hipStream_t stream) {
  const float* q  = (const float*)d_in[0];
  const float* k  = (const float*)d_in[1];
  const float* v  = (const float*)d_in[2];
  const int*  msk = (const int*)d_in[3];
  const float* Wq = (const float*)d_in[4];
  const float* Wk = (const float*)d_in[5];
  const float* Wv = (const float*)d_in[6];
  const float* Wo = (const float*)d_in[7];

  const size_t SZ_T = 16777216;  // 8192*1024*2
  const size_t SZ_W = 2097152;   // 1024*1024*2
  char* ws = (char*)d_ws;
  short* qb  = (short*)(ws + 0 * SZ_T);
  short* kb  = (short*)(ws + 1 * SZ_T);
  short* vb  = (short*)(ws + 2 * SZ_T);
  short* Qp  = (short*)(ws + 3 * SZ_T);
  short* Kp  = (short*)(ws + 4 * SZ_T);
  short* Vp  = (short*)(ws + 5 * SZ_T);
  short* Vt  = (short*)(ws + 6 * SZ_T);
  short* X   = (short*)(ws + 7 * SZ_T);
  short* wqb = (short*)(ws + 8 * SZ_T);
  short* wkb = (short*)(ws + 8 * SZ_T + 1 * SZ_W);
  short* wvb = (short*)(ws + 8 * SZ_T + 2 * SZ_W);
  short* wob = (short*)(ws + 8 * SZ_T + 3 * SZ_W);
  void*  mb  = (void*)(ws + 8 * SZ_T + 4 * SZ_W);
  if (ws_size < 8 * SZ_T + 5 * SZ_W) return;

  cast_f32_bf16<<<8192, 256, 0, stream>>>(q, qb, 2097152);
  cast_f32_bf16<<<8192, 256, 0, stream>>>(k, kb, 2097152);
  cast_f32_bf16<<<8192, 256, 0, stream>>>(v, vb, 2097152);
  cast_f32_bf16<<<1024, 256, 0, stream>>>(Wq, wqb, 262144);
  cast_f32_bf16<<<1024, 256, 0, stream>>>(Wk, wkb, 262144);
  cast_f32_bf16<<<1024, 256, 0, stream>>>(Wv, wvb, 262144);
  cast_f32_bf16<<<1024, 256, 0, stream>>>(Wo, wob, 262144);
  pack_mask<<<2048, 256, 0, stream>>>(msk, (ull*)mb);

  gemm_bt<0><<<512, 256, 0, stream>>>(qb, wqb, Qp);
  gemm_bt<0><<<512, 256, 0, stream>>>(kb, wkb, Kp);
  gemm_bt<0><<<512, 256, 0, stream>>>(vb, wvb, Vp);
  transpose_v<<<dim3(32, 64), 256, 0, stream>>>(Vp, Vt);
  attn_fwd<<<1024, 256, 0, stream>>>(Qp, Kp, Vt, (const ull*)mb, X);
  gemm_bt<1><<<512, 256, 0, stream>>>(X, wob, d_out);
}

// Round 3
// 291.920 us; speedup vs baseline: 2.1061x; 1.2302x over previous
//
#include <hip/hip_runtime.h>

// MHA: B=4, S=2048, D=1024, H=16, dk=64.
// cast f32->bf16 (Wq pre-scaled by log2e/8 -> scores in log2 domain),
// pack mask bits, fused QKV GEMM (head-major out), V transpose,
// flash attention (swapped-QK^T, BKV=64, XOR-swizzled LDS, defer-max,
// perm-packed P, single-buffered V, 4 blocks/CU), output GEMM (f32 out).

typedef __attribute__((ext_vector_type(8))) short frag8;   // 8 bf16 = 4 VGPR
typedef __attribute__((ext_vector_type(4))) float f32x4;
typedef unsigned long long ull;

#define MFMA16(a,b,c) __builtin_amdgcn_mfma_f32_16x16x32_bf16((a),(b),(c),0,0,0)

__device__ __forceinline__ short f2bf(float f) {
  union { float f; unsigned u; } x; x.f = f;
  unsigned r = (x.u + 0x7fffu + ((x.u >> 16) & 1u)) >> 16;  // RNE
  return (short)r;
}

// pack two f32 -> two bf16 (round-half-up) in one v_perm_b32
__device__ __forceinline__ unsigned pkbf(float lo, float hi) {
  union { float f; unsigned u; } a, b;
  a.f = lo; b.f = hi;
  return __builtin_amdgcn_perm(b.u + 0x8000u, a.u + 0x8000u, 0x07060302u);
}

__device__ __forceinline__ void gl16(const void* g, void* l) {
  __builtin_amdgcn_global_load_lds(
      (const __attribute__((address_space(1))) unsigned*)g,
      (__attribute__((address_space(3))) unsigned*)l, 16, 0, 0);
}

// ---------------- casts ----------------
__global__ __launch_bounds__(256) void cast_qkv(
    const float* __restrict__ q, const float* __restrict__ k,
    const float* __restrict__ v, short* __restrict__ qo,
    short* __restrict__ ko, short* __restrict__ vo) {
  int z = blockIdx.x >> 13;
  int i = (blockIdx.x & 8191) * 256 + threadIdx.x;
  const float* s = z == 0 ? q : z == 1 ? k : v;
  short* d = z == 0 ? qo : z == 1 ? ko : vo;
  float4 f = ((const float4*)s)[i];
  short4 o;
  o.x = f2bf(f.x); o.y = f2bf(f.y); o.z = f2bf(f.z); o.w = f2bf(f.w);
  ((short4*)d)[i] = o;
}

// Wq scaled by log2e/8 so QK^T scores land in log2 domain pre-scaled.
__global__ __launch_bounds__(256) void cast_w(
    const float* __restrict__ wq, const float* __restrict__ wk,
    const float* __restrict__ wv, const float* __restrict__ wo,
    short* __restrict__ oq, short* __restrict__ ok,
    short* __restrict__ ov, short* __restrict__ oo) {
  int z = blockIdx.x >> 10;
  int i = (blockIdx.x & 1023) * 256 + threadIdx.x;
  const float* s = z == 0 ? wq : z == 1 ? wk : z == 2 ? wv : wo;
  short* d = z == 0 ? oq : z == 1 ? ok : z == 2 ? ov : oo;
  float sc = (z == 0) ? 0.18033688011f : 1.0f;  // log2(e)/8
  float4 f = ((const float4*)s)[i];
  short4 o;
  o.x = f2bf(f.x * sc); o.y = f2bf(f.y * sc);
  o.z = f2bf(f.z * sc); o.w = f2bf(f.w * sc);
  ((short4*)d)[i] = o;
}

// ---------------- mask int32 -> bitpack via ballot ----------------
__global__ __launch_bounds__(256) void pack_mask(
    const int* __restrict__ mask, ull* __restrict__ bits) {
  int wv = threadIdx.x >> 6, l = threadIdx.x & 63;
  size_t row = (size_t)blockIdx.x * 4 + wv;   // 0..8191 = b*2048+q
  const int* src = mask + row * 2048;
  for (int c = 0; c < 2048; c += 64) {
    ull bl = __ballot(src[c + l] != 0);
    if (l == 0) bits[row * 32 + (c >> 6)] = bl;
  }
}

// ---------------- GEMM body: out[m][n] = sum_k A[m][k]*W[n][k] ----------
template <int MODE>
__device__ __forceinline__ void gemm_body(const short* __restrict__ A,
                                          const short* __restrict__ W,
                                          void* __restrict__ outp, int bid) {
  __shared__ short As[2][128 * 32];
  __shared__ short Bs[2][128 * 32];
  const int t = threadIdx.x;
  const int l = t & 63, wv = t >> 6;
  const int lg = l >> 4, lr = l & 15;
  const int wm = (wv >> 1) * 64, wn = (wv & 1) * 64;
  const int m0 = (bid >> 3) * 128;
  const int n0 = (bid & 7) * 128;

  auto stage = [&](int buf, int kt) {
    const int k0 = kt * 32;
#pragma unroll
    for (int c = 0; c < 2; ++c) {
      int idx = c * 256 + t;
      int row = idx >> 2, ch = (idx & 3) * 8;
      gl16(A + (size_t)(m0 + row) * 1024 + k0 + ch, &As[buf][idx * 8]);
      gl16(W + (size_t)(n0 + row) * 1024 + k0 + ch, &Bs[buf][idx * 8]);
    }
  };

  f32x4 acc[4][4] = {};
  stage(0, 0);
  asm volatile("s_waitcnt vmcnt(0)" ::: "memory");
  __syncthreads();
  int buf = 0;
  for (int kt = 0; kt < 32; ++kt) {
    if (kt + 1 < 32) stage(buf ^ 1, kt + 1);
    frag8 af[4], bf[4];
#pragma unroll
    for (int i = 0; i < 4; ++i) {
      af[i] = *(const frag8*)&As[buf][(wm + i * 16 + lr) * 32 + 8 * lg];
      bf[i] = *(const frag8*)&Bs[buf][(wn + i * 16 + lr) * 32 + 8 * lg];
    }
    __builtin_amdgcn_s_setprio(1);
#pragma unroll
    for (int mi = 0; mi < 4; ++mi)
#pragma unroll
      for (int ni = 0; ni < 4; ++ni)
        acc[mi][ni] = MFMA16(af[mi], bf[ni], acc[mi][ni]);
    __builtin_amdgcn_s_setprio(0);
    asm volatile("s_waitcnt vmcnt(0)" ::: "memory");
    __syncthreads();
    buf ^= 1;
  }

#pragma unroll
  for (int mi = 0; mi < 4; ++mi)
#pragma unroll
    for (int ni = 0; ni < 4; ++ni)
#pragma unroll
      for (int r = 0; r < 4; ++r) {
        int m = m0 + wm + mi * 16 + 4 * lg + r;
        int n = n0 + wn + ni * 16 + lr;
        if (MODE == 0) {
          int b = m >> 11, s = m & 2047, h = n >> 6, dk = n & 63;
          ((short*)outp)[(((size_t)b * 16 + h) * 2048 + s) * 64 + dk] =
              f2bf(acc[mi][ni][r]);
        } else {
          ((float*)outp)[(size_t)m * 1024 + n] = acc[mi][ni][r];
        }
      }
}

__global__ __launch_bounds__(256) void gemm_qkv(
    const short* __restrict__ A0, const short* __restrict__ A1,
    const short* __restrict__ A2, const short* __restrict__ W0,
    const short* __restrict__ W1, const short* __restrict__ W2,
    short* __restrict__ O0, short* __restrict__ O1, short* __restrict__ O2) {
  int wg = (blockIdx.x & 7) * 192 + (blockIdx.x >> 3);  // XCD chunk swizzle
  int z = wg >> 9, bid = wg & 511;
  const short* A = z == 0 ? A0 : z == 1 ? A1 : A2;
  const short* W = z == 0 ? W0 : z == 1 ? W1 : W2;
  short* O = z == 0 ? O0 : z == 1 ? O1 : O2;
  gemm_body<0>(A, W, O, bid);
}

__global__ __launch_bounds__(256) void gemm_o(
    const short* __restrict__ A, const short* __restrict__ W,
    float* __restrict__ O) {
  int bid = (blockIdx.x & 7) * 64 + (blockIdx.x >> 3);
  gemm_body<1>(A, W, O, bid);
}

// ---------------- V [bh][s][64] -> Vt [bh][64][s] ----------------
__global__ __launch_bounds__(256) void transpose_v(
    const short* __restrict__ Vp, short* __restrict__ Vt) {
  __shared__ short lds[64 * 72];
  int bh = blockIdx.y, s0 = blockIdx.x * 64;
  int t = threadIdx.x;
  int rr = t >> 3, c0 = (t & 7) * 8;
#pragma unroll
  for (int half = 0; half < 2; ++half) {
    int r = half * 32 + rr;
    frag8 v = *(const frag8*)(Vp + ((size_t)bh * 2048 + s0 + r) * 64 + c0);
#pragma unroll
    for (int j = 0; j < 8; ++j) lds[r * 72 + c0 + j] = v[j];
  }
  __syncthreads();
#pragma unroll
  for (int half = 0; half < 2; ++half) {
    int d = half * 32 + rr;
    frag8 o;
#pragma unroll
    for (int j = 0; j < 8; ++j) o[j] = lds[(c0 + j) * 72 + d];
    *(frag8*)(Vt + ((size_t)bh * 64 + d) * 2048 + s0 + c0) = o;
  }
}

// ---------------- flash attention (swapped QK^T, log2 domain) ----------
// block = (b,h, 128 q rows); 4 waves x 32 q rows; BKV=64.
// Scores arrive pre-scaled by log2e/8 (folded into Wq) -> P = exp2(s - m).
// Defer-max: mrun init 0, rescale only when row-max grows past +11.
__global__ __launch_bounds__(256, 4) void attn_fwd(
    const short* __restrict__ Qp, const short* __restrict__ Kp,
    const short* __restrict__ Vt, const ull* __restrict__ mb64,
    short* __restrict__ X) {
  __shared__ short Ks[2][64 * 64];   // [kv][d], double-buffered
  __shared__ short Vs[64 * 64];      // [d][kv], single-buffered
  __shared__ short Ps[4][32 * 64];   // per-wave P [q][kv]

  const int wg = (blockIdx.x & 7) * 128 + (blockIdx.x >> 3);  // XCD swizzle
  const int qt = wg & 15, bh = wg >> 4;
  const int b = bh >> 4, h = bh & 15;
  const int t = threadIdx.x;
  const int l = t & 63, wv = t >> 6;
  const int lg = l >> 4, lr = l & 15;
  const int q0 = qt * 128 + wv * 32;
  const int qrow_base = b << 11;

  // Q fragments (B-operand): Q[q=qb*16+lr][d=kc*32+8lg..+7]
  frag8 qf[2][2];
  const short* Qb = Qp + ((size_t)bh * 2048 + q0) * 64;
#pragma unroll
  for (int qb = 0; qb < 2; ++qb)
#pragma unroll
    for (int kc = 0; kc < 2; ++kc)
      qf[qb][kc] = *(const frag8*)(Qb + (qb * 16 + lr) * 64 + kc * 32 + 8 * lg);

  f32x4 acc[4][2] = {};
  float mrun[2] = {0.f, 0.f}, lrun[2] = {0.f, 0.f};

  const size_t kbase = (size_t)bh * 2048 * 64;
  const size_t vbase = (size_t)bh * 64 * 2048;
  short* Pw = &Ps[wv][0];
  const int sx = lr & 7;

  auto stageK = [&](int buf, int kt) {
#pragma unroll
    for (int p = 0; p < 2; ++p) {
      int idx = p * 256 + t;
      int row = idx >> 3, c = idx & 7;
      int cs = (c ^ (row & 7)) * 8;
      gl16(Kp + kbase + (size_t)(kt * 64 + row) * 64 + cs, &Ks[buf][idx * 8]);
    }
  };
  auto stageV = [&](int kt) {
#pragma unroll
    for (int p = 0; p < 2; ++p) {
      int idx = p * 256 + t;
      int row = idx >> 3, c = idx & 7;
      int cs = (c ^ (row & 7)) * 8;
      gl16(Vt + vbase + (size_t)row * 2048 + kt * 64 + cs, &Vs[idx * 8]);
    }
  };

  stageK(0, 0);
  asm volatile("s_waitcnt vmcnt(0)" ::: "memory");
  __syncthreads();
  int buf = 0;

  for (int kt = 0; kt < 32; ++kt) {
    stageV(kt);                        // 2 loads (oldest)
    stageK(buf ^ 1, (kt + 1) & 31);    // 2 loads (youngest; wraps, uniform)
    ull mw[2];
    mw[0] = mb64[(size_t)(qrow_base + q0 + lr) * 32 + kt];
    mw[1] = mb64[(size_t)(qrow_base + q0 + 16 + lr) * 32 + kt];

    // QK^T (swapped): S^T[kv=nb*16+4lg+r][q=qb*16+lr]
    f32x4 s[4][2] = {};
    __builtin_amdgcn_s_setprio(1);
#pragma unroll
    for (int nb = 0; nb < 4; ++nb) {
      const int ro = (nb * 16 + lr) * 64;
      frag8 k0 = *(const frag8*)&Ks[buf][ro + ((0 + lg) ^ sx) * 8];
      frag8 k1 = *(const frag8*)&Ks[buf][ro + ((4 + lg) ^ sx) * 8];
#pragma unroll
      for (int qb = 0; qb < 2; ++qb) {
        s[nb][qb] = MFMA16(k0, qf[qb][0], s[nb][qb]);
        s[nb][qb] = MFMA16(k1, qf[qb][1], s[nb][qb]);
      }
    }
    __builtin_amdgcn_s_setprio(0);

    // masked online softmax in log2 domain (defer-max)
#pragma unroll
    for (int qb = 0; qb < 2; ++qb) {
      float pv[4][4];
      float tm = -1e30f;
#pragma unroll
      for (int nb = 0; nb < 4; ++nb) {
        unsigned nib = (unsigned)(mw[qb] >> (nb * 16 + 4 * lg)) & 0xFu;
#pragma unroll
        for (int r = 0; r < 4; ++r)
          pv[nb][r] = ((nib >> r) & 1u) ? s[nb][qb][r] : -1e30f;
        tm = fmaxf(fmaxf(fmaxf(pv[nb][0], pv[nb][1]),
                         fmaxf(pv[nb][2], pv[nb][3])), tm);
      }
      tm = fmaxf(tm, __shfl_xor(tm, 16));
      tm = fmaxf(tm, __shfl_xor(tm, 32));
      float mn = mrun[qb];
      float fac = 1.f;
      bool resc = !__all(tm - mn <= 11.0f);
      if (resc) {
        mn = fmaxf(mn, tm);
        fac = __builtin_amdgcn_exp2f(mrun[qb] - mn);
        mrun[qb] = mn;
      }
      float ts = 0.f;
      const int q64 = (qb * 16 + lr) * 64;
#pragma unroll
      for (int nb = 0; nb < 4; ++nb) {
        float e0 = __builtin_amdgcn_exp2f(pv[nb][0] - mn);
        float e1 = __builtin_amdgcn_exp2f(pv[nb][1] - mn);
        float e2 = __builtin_amdgcn_exp2f(pv[nb][2] - mn);
        float e3 = __builtin_amdgcn_exp2f(pv[nb][3] - mn);
        ts += (e0 + e1) + (e2 + e3);
        uint2 w;
        w.x = pkbf(e0, e1);
        w.y = pkbf(e2, e3);
        int sw = ((2 * nb + (lg >> 1)) ^ sx) * 8 + 4 * (lg & 1);
        *(uint2*)&Pw[q64 + sw] = w;
      }
      ts += __shfl_xor(ts, 16);
      ts += __shfl_xor(ts, 32);
      if (resc) {
        lrun[qb] = lrun[qb] * fac + ts;
#pragma unroll
        for (int db = 0; db < 4; ++db)
#pragma unroll
          for (int j = 0; j < 4; ++j) acc[db][qb][j] *= fac;
      } else {
        lrun[qb] += ts;
      }
    }

    // V(kt) ready: 2 youngest (K) may stay in flight
    asm volatile("s_waitcnt vmcnt(2)" ::: "memory");
    __syncthreads();

    // PV: B-frag P[q=qb*16+lr][kv=kc*32+8lg..+7]
    frag8 pf[2][2];
#pragma unroll
    for (int qb = 0; qb < 2; ++qb)
#pragma unroll
      for (int kc = 0; kc < 2; ++kc)
        pf[qb][kc] = *(const frag8*)&Pw[(qb * 16 + lr) * 64 +
                                        ((kc * 4 + lg) ^ sx) * 8];
    __builtin_amdgcn_s_setprio(1);
#pragma unroll
    for (int db = 0; db < 4; ++db) {
      const int ro = (db * 16 + lr) * 64;
      frag8 v0 = *(const frag8*)&Vs[ro + ((0 + lg) ^ sx) * 8];
      frag8 v1 = *(const frag8*)&Vs[ro + ((4 + lg) ^ sx) * 8];
#pragma unroll
      for (int qb = 0; qb < 2; ++qb) {
        acc[db][qb] = MFMA16(v0, pf[qb][0], acc[db][qb]);
        acc[db][qb] = MFMA16(v1, pf[qb][1], acc[db][qb]);
      }
    }
    __builtin_amdgcn_s_setprio(0);

    asm volatile("s_waitcnt vmcnt(0)" ::: "memory");
    __syncthreads();
    buf ^= 1;
  }

  // epilogue: X[b][q][h*64+d] = O^T[d][q] / l
#pragma unroll
  for (int qb = 0; qb < 2; ++qb) {
    float inv = 1.0f / fmaxf(lrun[qb], 1e-30f);
    int q = q0 + qb * 16 + lr;
    size_t base = (size_t)(qrow_base + q) * 1024 + h * 64 + 4 * lg;
#pragma unroll
    for (int db = 0; db < 4; ++db) {
      uint2 o;
      o.x = pkbf(acc[db][qb][0] * inv, acc[db][qb][1] * inv);
      o.y = pkbf(acc[db][qb][2] * inv, acc[db][qb][3] * inv);
      *(uint2*)&X[base + db * 16] = o;
    }
  }
}

// ---------------- launch ----------------
extern "C" void kernel_launch(void* const* d_in, const int* in_sizes, int n_in,
                              void* d_out, int out_size, void* d_ws,
                              size_t ws_size, hipStream_t stream) {
  const float* q  = (const float*)d_in[0];
  const float* k  = (const float*)d_in[1];
  const float* v  = (const float*)d_in[2];
  const int*  msk = (const int*)d_in[3];
  const float* Wq = (const float*)d_in[4];
  const float* Wk = (const float*)d_in[5];
  const float* Wv = (const float*)d_in[6];
  const float* Wo = (const float*)d_in[7];

  const size_t SZ_T = 16777216;  // 8192*1024*2
  const size_t SZ_W = 2097152;   // 1024*1024*2
  char* ws = (char*)d_ws;
  short* qb  = (short*)(ws + 0 * SZ_T);
  short* kb  = (short*)(ws + 1 * SZ_T);
  short* vb  = (short*)(ws + 2 * SZ_T);
  short* Qp  = (short*)(ws + 3 * SZ_T);
  short* Kp  = (short*)(ws + 4 * SZ_T);
  short* Vp  = (short*)(ws + 5 * SZ_T);
  short* Vt  = (short*)(ws + 6 * SZ_T);
  short* X   = (short*)(ws + 7 * SZ_T);
  short* wqb = (short*)(ws + 8 * SZ_T);
  short* wkb = (short*)(ws + 8 * SZ_T + 1 * SZ_W);
  short* wvb = (short*)(ws + 8 * SZ_T + 2 * SZ_W);
  short* wob = (short*)(ws + 8 * SZ_T + 3 * SZ_W);
  void*  mb  = (void*)(ws + 8 * SZ_T + 4 * SZ_W);
  if (ws_size < 8 * SZ_T + 5 * SZ_W) return;

  cast_qkv<<<24576, 256, 0, stream>>>(q, k, v, qb, kb, vb);
  cast_w<<<4096, 256, 0, stream>>>(Wq, Wk, Wv, Wo, wqb, wkb, wvb, wob);
  pack_mask<<<2048, 256, 0, stream>>>(msk, (ull*)mb);

  gemm_qkv<<<1536, 256, 0, stream>>>(qb, kb, vb, wqb, wkb, wvb, Qp, Kp, Vp);
  transpose_v<<<dim3(32, 64), 256, 0, stream>>>(Vp, Vt);
  attn_fwd<<<1024, 256, 0, stream>>>(Qp, Kp, Vt, (const ull*)mb, X);
  gemm_o<<<512, 256, 0, stream>>>(X, wob, (float*)d_out);
}

// Round 5
// 289.542 us; speedup vs baseline: 2.1234x; 1.0082x over previous
//
#include <hip/hip_runtime.h>

// MHA: B=4, S=2048, D=1024, H=16, dk=64.
// cast f32->bf16 (Wq pre-scaled by log2e/8 -> scores in log2 domain),
// fused QKV GEMM (head-major out), V transpose, mask -> halfword AND-masks
// in S^T fragment order, flash attention (swapped-QK^T, defer-max exp2
// softmax, post-pack AND masking, BKV=64, XOR-swizzled LDS), output GEMM.

typedef __attribute__((ext_vector_type(8))) short frag8;   // 8 bf16 = 4 VGPR
typedef __attribute__((ext_vector_type(4))) float f32x4;
typedef unsigned long long ull;

#define MFMA16(a,b,c) __builtin_amdgcn_mfma_f32_16x16x32_bf16((a),(b),(c),0,0,0)

__device__ __forceinline__ short f2bf(float f) {
  union { float f; unsigned u; } x; x.f = f;
  unsigned r = (x.u + 0x7fffu + ((x.u >> 16) & 1u)) >> 16;  // RNE
  return (short)r;
}

// pack two f32 -> two bf16 (round-half-up) in one v_perm_b32 (R3-proven)
__device__ __forceinline__ unsigned pkbf(float lo, float hi) {
  union { float f; unsigned u; } a, b;
  a.f = lo; b.f = hi;
  return __builtin_amdgcn_perm(b.u + 0x8000u, a.u + 0x8000u, 0x07060302u);
}

__device__ __forceinline__ void gl16(const void* g, void* l) {
  __builtin_amdgcn_global_load_lds(
      (const __attribute__((address_space(1))) unsigned*)g,
      (__attribute__((address_space(3))) unsigned*)l, 16, 0, 0);
}

// ---------------- casts ----------------
__global__ __launch_bounds__(256) void cast_qkv(
    const float* __restrict__ q, const float* __restrict__ k,
    const float* __restrict__ v, short* __restrict__ qo,
    short* __restrict__ ko, short* __restrict__ vo) {
  int z = blockIdx.x >> 13;
  int i = (blockIdx.x & 8191) * 256 + threadIdx.x;
  const float* s = z == 0 ? q : z == 1 ? k : v;
  short* d = z == 0 ? qo : z == 1 ? ko : vo;
  float4 f = ((const float4*)s)[i];
  short4 o;
  o.x = f2bf(f.x); o.y = f2bf(f.y); o.z = f2bf(f.z); o.w = f2bf(f.w);
  ((short4*)d)[i] = o;
}

// Wq scaled by log2e/8 so QK^T scores land in log2 domain pre-scaled.
__global__ __launch_bounds__(256) void cast_w(
    const float* __restrict__ wq, const float* __restrict__ wk,
    const float* __restrict__ wv, const float* __restrict__ wo,
    short* __restrict__ oq, short* __restrict__ ok,
    short* __restrict__ ov, short* __restrict__ oo) {
  int z = blockIdx.x >> 10;
  int i = (blockIdx.x & 1023) * 256 + threadIdx.x;
  const float* s = z == 0 ? wq : z == 1 ? wk : z == 2 ? wv : wo;
  short* d = z == 0 ? oq : z == 1 ? ok : z == 2 ? ov : oo;
  float sc = (z == 0) ? 0.18033688011f : 1.0f;  // log2(e)/8
  float4 f = ((const float4*)s)[i];
  short4 o;
  o.x = f2bf(f.x * sc); o.y = f2bf(f.y * sc);
  o.z = f2bf(f.z * sc); o.w = f2bf(f.w * sc);
  ((short4*)d)[i] = o;
}

// ---------------- mask -> halfword AND-masks in S^T fragment order -------
// uint2 at [(bgrp*32+kt)*512 + (qb*4+nb)*64 + l], bgrp = b*64 + (q>>5)
// halfwords {0xFFFF,0} for kv = kt*64+nb*16+lg*4+{0,1 | 2,3}, q = g*32+qb*16+lr
__global__ __launch_bounds__(256) void mask_expand(
    const int* __restrict__ mask, uint2* __restrict__ mexp) {
  int bgrp = blockIdx.x >> 2;      // b*64+g
  int kq = blockIdx.x & 3;
  int b = bgrp >> 6, g = bgrp & 63;
  int t = threadIdx.x;
  int l = t & 63, nb = t >> 6;
  int lg = l >> 4, lr = l & 15;
#pragma unroll
  for (int qb = 0; qb < 2; ++qb) {
    const int* row = mask + ((size_t)b * 2048 + g * 32 + qb * 16 + lr) * 2048;
#pragma unroll
    for (int i = 0; i < 8; ++i) {
      int kt = kq * 8 + i;
      int4 m = *(const int4*)(row + kt * 64 + nb * 16 + lg * 4);
      uint2 w;
      w.x = (m.x ? 0xFFFFu : 0u) | (m.y ? 0xFFFF0000u : 0u);
      w.y = (m.z ? 0xFFFFu : 0u) | (m.w ? 0xFFFF0000u : 0u);
      mexp[((size_t)bgrp * 32 + kt) * 512 + (qb * 4 + nb) * 64 + l] = w;
    }
  }
}

// ---------------- GEMM body: out[m][n] = sum_k A[m][k]*W[n][k] ----------
// MODE 0: bf16 head-major [B][H][S][64]. MODE 1: f32 [M][1024].
template <int MODE>
__device__ __forceinline__ void gemm_body(const short* __restrict__ A,
                                          const short* __restrict__ W,
                                          void* __restrict__ outp, int bid) {
  __shared__ short As[2][128 * 32];
  __shared__ short Bs[2][128 * 32];
  const int t = threadIdx.x;
  const int l = t & 63, wv = t >> 6;
  const int lg = l >> 4, lr = l & 15;
  const int wm = (wv >> 1) * 64, wn = (wv & 1) * 64;
  const int m0 = (bid >> 3) * 128;
  const int n0 = (bid & 7) * 128;

  auto stage = [&](int buf, int kt) {
    const int k0 = kt * 32;
#pragma unroll
    for (int c = 0; c < 2; ++c) {
      int idx = c * 256 + t;
      int row = idx >> 2, ch = (idx & 3) * 8;
      gl16(A + (size_t)(m0 + row) * 1024 + k0 + ch, &As[buf][idx * 8]);
      gl16(W + (size_t)(n0 + row) * 1024 + k0 + ch, &Bs[buf][idx * 8]);
    }
  };

  f32x4 acc[4][4] = {};
  stage(0, 0);
  asm volatile("s_waitcnt vmcnt(0)" ::: "memory");
  __syncthreads();
  int buf = 0;
  for (int kt = 0; kt < 32; ++kt) {
    if (kt + 1 < 32) stage(buf ^ 1, kt + 1);
    frag8 af[4], bf[4];
#pragma unroll
    for (int i = 0; i < 4; ++i) {
      af[i] = *(const frag8*)&As[buf][(wm + i * 16 + lr) * 32 + 8 * lg];
      bf[i] = *(const frag8*)&Bs[buf][(wn + i * 16 + lr) * 32 + 8 * lg];
    }
    __builtin_amdgcn_s_setprio(1);
#pragma unroll
    for (int mi = 0; mi < 4; ++mi)
#pragma unroll
      for (int ni = 0; ni < 4; ++ni)
        acc[mi][ni] = MFMA16(af[mi], bf[ni], acc[mi][ni]);
    __builtin_amdgcn_s_setprio(0);
    asm volatile("s_waitcnt vmcnt(0)" ::: "memory");
    __syncthreads();
    buf ^= 1;
  }

#pragma unroll
  for (int mi = 0; mi < 4; ++mi)
#pragma unroll
    for (int ni = 0; ni < 4; ++ni)
#pragma unroll
      for (int r = 0; r < 4; ++r) {
        int m = m0 + wm + mi * 16 + 4 * lg + r;
        int n = n0 + wn + ni * 16 + lr;
        if (MODE == 0) {
          int b = m >> 11, s = m & 2047, h = n >> 6, dk = n & 63;
          ((short*)outp)[(((size_t)b * 16 + h) * 2048 + s) * 64 + dk] =
              f2bf(acc[mi][ni][r]);
        } else {
          ((float*)outp)[(size_t)m * 1024 + n] = acc[mi][ni][r];
        }
      }
}

__global__ __launch_bounds__(256) void gemm_qkv(
    const short* __restrict__ A0, const short* __restrict__ A1,
    const short* __restrict__ A2, const short* __restrict__ W0,
    const short* __restrict__ W1, const short* __restrict__ W2,
    short* __restrict__ O0, short* __restrict__ O1, short* __restrict__ O2) {
  int wg = (blockIdx.x & 7) * 192 + (blockIdx.x >> 3);  // XCD chunk swizzle
  int z = wg >> 9, bid = wg & 511;
  const short* A = z == 0 ? A0 : z == 1 ? A1 : A2;
  const short* W = z == 0 ? W0 : z == 1 ? W1 : W2;
  short* O = z == 0 ? O0 : z == 1 ? O1 : O2;
  gemm_body<0>(A, W, O, bid);
}

__global__ __launch_bounds__(256) void gemm_o(
    const short* __restrict__ A, const short* __restrict__ W,
    float* __restrict__ O) {
  int bid = (blockIdx.x & 7) * 64 + (blockIdx.x >> 3);
  gemm_body<1>(A, W, O, bid);
}

// ---------------- V [bh][s][64] -> Vt [bh][64][s] ----------------
__global__ __launch_bounds__(256) void transpose_v(
    const short* __restrict__ Vp, short* __restrict__ Vt) {
  __shared__ short lds[64 * 72];
  int bh = blockIdx.y, s0 = blockIdx.x * 64;
  int t = threadIdx.x;
  int rr = t >> 3, c0 = (t & 7) * 8;
#pragma unroll
  for (int half = 0; half < 2; ++half) {
    int r = half * 32 + rr;
    frag8 v = *(const frag8*)(Vp + ((size_t)bh * 2048 + s0 + r) * 64 + c0);
#pragma unroll
    for (int j = 0; j < 8; ++j) lds[r * 72 + c0 + j] = v[j];
  }
  __syncthreads();
#pragma unroll
  for (int half = 0; half < 2; ++half) {
    int d = half * 32 + rr;
    frag8 o;
#pragma unroll
    for (int j = 0; j < 8; ++j) o[j] = lds[(c0 + j) * 72 + d];
    *(frag8*)(Vt + ((size_t)bh * 64 + d) * 2048 + s0 + c0) = o;
  }
}

// ---------------- flash attention (swapped QK^T, log2 domain) ----------
// block = (b,h, 128 q rows); 4 waves x 32 q rows; BKV=64.
// Scores pre-scaled by log2e/8 (in Wq). Row-max from RAW scores (exact:
// common scale cancels in O = sum(PV)/sum(P)); defer-max THR=11.
// Mask applied as halfword AND on packed bf16 P; ts from masked values.
__global__ __launch_bounds__(256, 4) void attn_fwd(
    const short* __restrict__ Qp, const short* __restrict__ Kp,
    const short* __restrict__ Vt, const uint2* __restrict__ mexp,
    short* __restrict__ X) {
  __shared__ short Ks[2][64 * 64];   // [kv][d], double-buffered
  __shared__ short Vs[64 * 64];      // [d][kv], single-buffered
  __shared__ short Ps[4][32 * 64];   // per-wave P [q][kv]

  const int wg = (blockIdx.x & 7) * 128 + (blockIdx.x >> 3);  // XCD swizzle
  const int qt = wg & 15, bh = wg >> 4;
  const int b = bh >> 4, h = bh & 15;
  const int t = threadIdx.x;
  const int l = t & 63, wv = t >> 6;
  const int lg = l >> 4, lr = l & 15;
  const int q0 = qt * 128 + wv * 32;
  const int qrow_base = b << 11;

  // Q fragments (B-operand): Q[q=qb*16+lr][d=kc*32+8lg..+7]
  frag8 qf[2][2];
  const short* Qb = Qp + ((size_t)bh * 2048 + q0) * 64;
#pragma unroll
  for (int qb = 0; qb < 2; ++qb)
#pragma unroll
    for (int kc = 0; kc < 2; ++kc)
      qf[qb][kc] = *(const frag8*)(Qb + (qb * 16 + lr) * 64 + kc * 32 + 8 * lg);

  f32x4 acc[4][2] = {};
  float mrun[2] = {0.f, 0.f}, lrun[2] = {0.f, 0.f};

  const size_t kbase = (size_t)bh * 2048 * 64;
  const size_t vbase = (size_t)bh * 64 * 2048;
  short* Pw = &Ps[wv][0];
  const int sx = lr & 7;
  const uint2* mrow = mexp + ((size_t)(b * 64 + qt * 4 + wv) * 32) * 512 + l;

  auto stageK = [&](int buf, int kt) {
#pragma unroll
    for (int p = 0; p < 2; ++p) {
      int idx = p * 256 + t;
      int row = idx >> 3, c = idx & 7;
      int cs = (c ^ (row & 7)) * 8;
      gl16(Kp + kbase + (size_t)(kt * 64 + row) * 64 + cs, &Ks[buf][idx * 8]);
    }
  };
  auto stageV = [&](int kt) {
#pragma unroll
    for (int p = 0; p < 2; ++p) {
      int idx = p * 256 + t;
      int row = idx >> 3, c = idx & 7;
      int cs = (c ^ (row & 7)) * 8;
      gl16(Vt + vbase + (size_t)row * 2048 + kt * 64 + cs, &Vs[idx * 8]);
    }
  };

  stageK(0, 0);
  asm volatile("s_waitcnt vmcnt(0)" ::: "memory");
  __syncthreads();
  int buf = 0;

  for (int kt = 0; kt < 32; ++kt) {
    // mask loads first, then V, then K -> counted vmcnt stays valid
    uint2 mk[2][4];
    const uint2* mt = mrow + kt * 512;
#pragma unroll
    for (int qb = 0; qb < 2; ++qb)
#pragma unroll
      for (int nb = 0; nb < 4; ++nb) mk[qb][nb] = mt[(qb * 4 + nb) * 64];
    asm volatile("" ::: "memory");
    stageV(kt);
    asm volatile("" ::: "memory");
    stageK(buf ^ 1, (kt + 1) & 31);

    // QK^T (swapped): S^T[kv=nb*16+4lg+r][q=qb*16+lr]
    f32x4 s[4][2] = {};
    __builtin_amdgcn_s_setprio(1);
#pragma unroll
    for (int nb = 0; nb < 4; ++nb) {
      const int ro = (nb * 16 + lr) * 64;
      frag8 k0 = *(const frag8*)&Ks[buf][ro + ((0 + lg) ^ sx) * 8];
      frag8 k1 = *(const frag8*)&Ks[buf][ro + ((4 + lg) ^ sx) * 8];
#pragma unroll
      for (int qb = 0; qb < 2; ++qb) {
        s[nb][qb] = MFMA16(k0, qf[qb][0], s[nb][qb]);
        s[nb][qb] = MFMA16(k1, qf[qb][1], s[nb][qb]);
      }
    }
    __builtin_amdgcn_s_setprio(0);

    // softmax: row-max from raw scores; P = exp2(s - mn) & mask (post-pack)
#pragma unroll
    for (int qb = 0; qb < 2; ++qb) {
      float tm = -1e30f;
#pragma unroll
      for (int nb = 0; nb < 4; ++nb)
        tm = fmaxf(tm, fmaxf(fmaxf(s[nb][qb][0], s[nb][qb][1]),
                             fmaxf(s[nb][qb][2], s[nb][qb][3])));
      tm = fmaxf(tm, __shfl_xor(tm, 16));
      tm = fmaxf(tm, __shfl_xor(tm, 32));
      float mn = mrun[qb];
      float fac = 1.f;
      bool resc = !__all(tm - mn <= 11.0f);
      if (resc) {
        mn = fmaxf(mn, tm);
        fac = __builtin_amdgcn_exp2f(mrun[qb] - mn);
        mrun[qb] = mn;
      }
      float ts = 0.f;
      const int q64 = (qb * 16 + lr) * 64;
#pragma unroll
      for (int nb = 0; nb < 4; ++nb) {
        float e0 = __builtin_amdgcn_exp2f(s[nb][qb][0] - mn);
        float e1 = __builtin_amdgcn_exp2f(s[nb][qb][1] - mn);
        float e2 = __builtin_amdgcn_exp2f(s[nb][qb][2] - mn);
        float e3 = __builtin_amdgcn_exp2f(s[nb][qb][3] - mn);
        unsigned w0 = pkbf(e0, e1) & mk[qb][nb].x;
        unsigned w1 = pkbf(e2, e3) & mk[qb][nb].y;
        ts += __uint_as_float(w0 << 16) + __uint_as_float(w0 & 0xFFFF0000u) +
              __uint_as_float(w1 << 16) + __uint_as_float(w1 & 0xFFFF0000u);
        uint2 w; w.x = w0; w.y = w1;
        int sw = ((2 * nb + (lg >> 1)) ^ sx) * 8 + 4 * (lg & 1);
        *(uint2*)&Pw[q64 + sw] = w;
      }
      ts += __shfl_xor(ts, 16);
      ts += __shfl_xor(ts, 32);
      if (resc) {
        lrun[qb] = lrun[qb] * fac + ts;
#pragma unroll
        for (int db = 0; db < 4; ++db)
#pragma unroll
          for (int j = 0; j < 4; ++j) acc[db][qb][j] *= fac;
      } else {
        lrun[qb] += ts;
      }
    }

    // V(kt) ready: 2 youngest (K prefetch) stay in flight
    asm volatile("s_waitcnt vmcnt(2)" ::: "memory");
    __syncthreads();

    // PV: B-frag P[q=qb*16+lr][kv=kc*32+8lg..+7]
    frag8 pf[2][2];
#pragma unroll
    for (int qb = 0; qb < 2; ++qb)
#pragma unroll
      for (int kc = 0; kc < 2; ++kc)
        pf[qb][kc] = *(const frag8*)&Pw[(qb * 16 + lr) * 64 +
                                        ((kc * 4 + lg) ^ sx) * 8];
    __builtin_amdgcn_s_setprio(1);
#pragma unroll
    for (int db = 0; db < 4; ++db) {
      const int ro = (db * 16 + lr) * 64;
      frag8 v0 = *(const frag8*)&Vs[ro + ((0 + lg) ^ sx) * 8];
      frag8 v1 = *(const frag8*)&Vs[ro + ((4 + lg) ^ sx) * 8];
#pragma unroll
      for (int qb = 0; qb < 2; ++qb) {
        acc[db][qb] = MFMA16(v0, pf[qb][0], acc[db][qb]);
        acc[db][qb] = MFMA16(v1, pf[qb][1], acc[db][qb]);
      }
    }
    __builtin_amdgcn_s_setprio(0);

    asm volatile("s_waitcnt vmcnt(0)" ::: "memory");
    __syncthreads();
    buf ^= 1;
  }

  // epilogue: X[b][q][h*64+d] = O^T[d][q] / l
#pragma unroll
  for (int qb = 0; qb < 2; ++qb) {
    float inv = 1.0f / fmaxf(lrun[qb], 1e-30f);
    int q = q0 + qb * 16 + lr;
    size_t base = (size_t)(qrow_base + q) * 1024 + h * 64 + 4 * lg;
#pragma unroll
    for (int db = 0; db < 4; ++db) {
      uint2 o;
      o.x = pkbf(acc[db][qb][0] * inv, acc[db][qb][1] * inv);
      o.y = pkbf(acc[db][qb][2] * inv, acc[db][qb][3] * inv);
      *(uint2*)&X[base + db * 16] = o;
    }
  }
}

// ---------------- launch ----------------
extern "C" void kernel_launch(void* const* d_in, const int* in_sizes, int n_in,
                              void* d_out, int out_size, void* d_ws,
                              size_t ws_size, hipStream_t stream) {
  const float* q  = (const float*)d_in[0];
  const float* k  = (const float*)d_in[1];
  const float* v  = (const float*)d_in[2];
  const int*  msk = (const int*)d_in[3];
  const float* Wq = (const float*)d_in[4];
  const float* Wk = (const float*)d_in[5];
  const float* Wv = (const float*)d_in[6];
  const float* Wo = (const float*)d_in[7];

  const size_t SZ_T = 16777216;  // 8192*1024*2
  const size_t SZ_W = 2097152;   // 1024*1024*2
  char* ws = (char*)d_ws;
  short* qb  = (short*)(ws + 0 * SZ_T);
  short* kb  = (short*)(ws + 1 * SZ_T);
  short* vb  = (short*)(ws + 2 * SZ_T);
  short* Qp  = (short*)(ws + 3 * SZ_T);
  short* Kp  = (short*)(ws + 4 * SZ_T);
  short* Vp  = (short*)(ws + 5 * SZ_T);
  short* Vt  = (short*)(ws + 6 * SZ_T);
  short* X   = (short*)(ws + 7 * SZ_T);
  short* wqb = (short*)(ws + 8 * SZ_T);
  short* wkb = (short*)(ws + 8 * SZ_T + 1 * SZ_W);
  short* wvb = (short*)(ws + 8 * SZ_T + 2 * SZ_W);
  short* wob = (short*)(ws + 8 * SZ_T + 3 * SZ_W);
  void*  mexp = (void*)(ws + 0 * SZ_T);  // 32MB over qb+kb (dead after gemm_qkv)
  if (ws_size < 8 * SZ_T + 4 * SZ_W) return;

  cast_qkv<<<24576, 256, 0, stream>>>(q, k, v, qb, kb, vb);
  cast_w<<<4096, 256, 0, stream>>>(Wq, Wk, Wv, Wo, wqb, wkb, wvb, wob);
  gemm_qkv<<<1536, 256, 0, stream>>>(qb, kb, vb, wqb, wkb, wvb, Qp, Kp, Vp);
  mask_expand<<<1024, 256, 0, stream>>>(msk, (uint2*)mexp);
  transpose_v<<<dim3(32, 64), 256, 0, stream>>>(Vp, Vt);
  attn_fwd<<<1024, 256, 0, stream>>>(Qp, Kp, Vt, (const uint2*)mexp, X);
  gemm_o<<<512, 256, 0, stream>>>(X, wob, (float*)d_out);
}